// Round 8
// baseline (39.013 us; speedup 1.0000x reference)
//
#include <hip/hip_runtime.h>
#include <hip/hip_bf16.h>

// EdgeNetwork: B=8, N=256, F_IN=64, F_OUT=64, MID=96
// out[b,n,o] = sum_m tanh( relu( [x_n, x_j(m), e_{b,n,m}] @ W1 + b1 ) @ W2 + b2 )[o]
// H[m,:] = A[b,n,:] + C[b,j(m),:] + e[m]*W1[128,:],  j = m + (m>=n)
// R8: occupancy push. LDS = sC only (53248 B -> 3 blocks/CU = 12 waves/CU,
// up from 8); reduction overlaid on sC after last use; 2 barriers total;
// per-nl e-values prefetched; Rs kept [nl][nt] in registers.
// tanh(v) = 1 - 2r, r = 1/(1+exp(2v));  out = 256 - 2*sum(r), invalid slot -> 0.5.

#define BATCH 8
#define NN 256
#define FIN 64
#define FOUT 64
#define MIDD 96
#define CPAD 104   // bf16 elems per padded row (208 B: 16B-aligned, 2-way-max banks)
#define NG 4       // n-values per block

typedef __attribute__((ext_vector_type(8))) short short8;  // 8 bf16
typedef __attribute__((ext_vector_type(4))) float f32x4;

#if __has_builtin(__builtin_amdgcn_exp2f)
#define EXP2F(x) __builtin_amdgcn_exp2f(x)
#else
#define EXP2F(x) exp2f(x)
#endif
#if __has_builtin(__builtin_amdgcn_rcpf)
#define RCPF(x) __builtin_amdgcn_rcpf(x)
#else
#define RCPF(x) (1.0f / (x))
#endif

#define TWO_LOG2E 2.8853900817779268f

__device__ __forceinline__ unsigned pack_bf16(float lo, float hi) {
    __hip_bfloat162 h2 = __float22bfloat162_rn(make_float2(lo, hi));
    union { __hip_bfloat162 h; unsigned u; } cv; cv.h = h2;
    return cv.u;
}

// ------------- precompute: A (f32), C (bf16 padded), W2T (bf16 padded) -------
__global__ __launch_bounds__(192) void edge_pre(
    const float* __restrict__ node,    // (B,N,64)
    const float* __restrict__ W1,      // (129,96)
    const float* __restrict__ b1,      // (96,)
    const float* __restrict__ W2,      // (96,64)
    float* __restrict__ A,             // (B*N,96) f32
    unsigned short* __restrict__ Cb16, // (B, N, CPAD) bf16
    unsigned short* __restrict__ W2T)  // (64, CPAD) bf16
{
    int blk = blockIdx.x;
    int tid = threadIdx.x;
    if (blk == BATCH * NN) {
        for (int idx = tid; idx < FOUT * CPAD; idx += 192) {
            int c = idx / CPAD, k = idx % CPAD;
            float v = (k < MIDD) ? W2[k * FOUT + c] : 0.f;
            union { __hip_bfloat16 h; unsigned short u; } cv;
            cv.h = __float2bfloat16(v);
            W2T[idx] = cv.u;
        }
        return;
    }
    __shared__ float x[FIN];
    if (tid < FIN) x[tid] = node[(size_t)blk * FIN + tid];
    __syncthreads();
    if (tid < MIDD) {
        int h = tid;
        float s = b1[h];
#pragma unroll
        for (int f = 0; f < FIN; ++f) s = fmaf(x[f], W1[f * MIDD + h], s);
        A[(size_t)blk * MIDD + h] = s;
    } else {
        int h = tid - MIDD;   // 0..95
        float s = 0.f;
#pragma unroll
        for (int f = 0; f < FIN; ++f) s = fmaf(x[f], W1[(FIN + f) * MIDD + h], s);
        union { __hip_bfloat16 hh; unsigned short u; } cv;
        cv.hh = __float2bfloat16(s);
        Cb16[(size_t)blk * CPAD + h] = cv.u;
        if (h < CPAD - MIDD) Cb16[(size_t)blk * CPAD + MIDD + h] = 0;  // pad
    }
}

// ------------- main: LDS-staged C[b], 4 n's per block, 12 waves/CU ------------
__global__ __launch_bounds__(256, 3) void edge_main3(
    const float* __restrict__ edge,          // (B,N,255)
    const float* __restrict__ A,             // (B*N,96)
    const unsigned short* __restrict__ Cb16, // (B,N,CPAD) bf16
    const float* __restrict__ W1,            // row 128 used
    const unsigned short* __restrict__ W2T,  // (64,CPAD) bf16
    const float* __restrict__ b2,            // (64,)
    float* __restrict__ out)                 // (B,N,64)
{
    __shared__ unsigned short sC[NN * CPAD];   // 53248 B; tail reused for reduce

    int blk = blockIdx.x;             // 0..511
    int b = blk >> 6;
    int n0 = (blk & 63) << 2;
    int tid = threadIdx.x;
    int w = tid >> 6, lane = tid & 63;
    int lo16 = lane & 15, hi = lane >> 4;

    // stage C[b] -> LDS, fully coalesced (3328 uint4)
    {
        const uint4* src = (const uint4*)(Cb16 + (size_t)b * NN * CPAD);
        uint4* dst = (uint4*)sC;
#pragma unroll
        for (int i = 0; i < 13; ++i) dst[i * 256 + tid] = src[i * 256 + tid];
    }

    // per-lane k-slices of W1[128]: k = ks*32 + hi*8 + 0..7
    float W24[24];
    {
        const float* Wbase = W1 + 128 * MIDD;
#pragma unroll
        for (int ks = 0; ks < 3; ++ks) {
            int k0 = ks * 32 + hi * 8;
            float4 w0 = *(const float4*)(Wbase + k0);
            float4 w1 = *(const float4*)(Wbase + k0 + 4);
            W24[ks*8+0]=w0.x; W24[ks*8+1]=w0.y; W24[ks*8+2]=w0.z; W24[ks*8+3]=w0.w;
            W24[ks*8+4]=w1.x; W24[ks*8+5]=w1.y; W24[ks*8+6]=w1.z; W24[ks*8+7]=w1.w;
        }
    }

    // B fragments from global W2T (one-time, L2-resident)
    short8 bf[4][3];
#pragma unroll
    for (int nt = 0; nt < 4; ++nt)
#pragma unroll
        for (int ks = 0; ks < 3; ++ks)
            bf[nt][ks] = *(const short8*)&W2T[(nt * 16 + lo16) * CPAD + ks * 32 + hi * 8];

    float c2[4], corr[4];   // 2*log2(e)*b2[col]; invalid-slot correction
#pragma unroll
    for (int nt = 0; nt < 4; ++nt) {
        c2[nt] = TWO_LOG2E * b2[nt * 16 + lo16];
        corr[nt] = 0.5f - RCPF(1.f + EXP2F(c2[nt]));
    }

    __syncthreads();

    float Rs[NG][4];
#pragma unroll
    for (int nl = 0; nl < NG; ++nl)
#pragma unroll
        for (int nt = 0; nt < 4; ++nt) Rs[nl][nt] = 0.f;

#pragma unroll 1
    for (int nl = 0; nl < NG; ++nl) {
        int n = n0 + nl;
        int bn = (b << 8) + n;

        // A-row slices (f32, per-n)
        float A24[24];
        {
            const float* Abase = A + (size_t)bn * MIDD;
#pragma unroll
            for (int ks = 0; ks < 3; ++ks) {
                int k0 = ks * 32 + hi * 8;
                float4 a0 = *(const float4*)(Abase + k0);
                float4 a1 = *(const float4*)(Abase + k0 + 4);
                A24[ks*8+0]=a0.x; A24[ks*8+1]=a0.y; A24[ks*8+2]=a0.z; A24[ks*8+3]=a0.w;
                A24[ks*8+4]=a1.x; A24[ks*8+5]=a1.y; A24[ks*8+6]=a1.z; A24[ks*8+7]=a1.w;
            }
        }
        const float* eg = edge + (size_t)bn * (NN - 1);

        // prefetch all 4 chunks' edge values (independent loads)
        float ev[4];
#pragma unroll
        for (int c = 0; c < 4; ++c) {
            int m = c * 64 + w * 16 + lo16;
            ev[c] = eg[m < NN - 1 ? m : NN - 2];
        }

#pragma unroll
        for (int chunk = 0; chunk < 4; ++chunk) {
            int m = chunk * 64 + w * 16 + lo16;
            bool valid = (m < NN - 1);
            unsigned mc = valid ? 0xFFFFFFFFu : 0u;
            int j = m + ((m >= n) ? 1 : 0);
            j = (j > 255) ? 255 : j;
            float e = ev[chunk];
            const unsigned short* crow = &sC[j * CPAD + hi * 8];

            short8 af[3];
#pragma unroll
            for (int ks = 0; ks < 3; ++ks) {
                uint4 q = *(const uint4*)(crow + ks * 32);   // ds_read_b128
                float c[8];
                c[0] = __uint_as_float(q.x << 16);
                c[1] = __uint_as_float(q.x & 0xFFFF0000u);
                c[2] = __uint_as_float(q.y << 16);
                c[3] = __uint_as_float(q.y & 0xFFFF0000u);
                c[4] = __uint_as_float(q.z << 16);
                c[5] = __uint_as_float(q.z & 0xFFFF0000u);
                c[6] = __uint_as_float(q.w << 16);
                c[7] = __uint_as_float(q.w & 0xFFFF0000u);
                float h[8];
#pragma unroll
                for (int i = 0; i < 8; ++i)
                    h[i] = fmaxf(fmaf(e, W24[ks*8+i], A24[ks*8+i] + c[i]), 0.f);
                union { unsigned u[4]; short8 s; } cv;
                cv.u[0] = pack_bf16(h[0], h[1]) & mc;
                cv.u[1] = pack_bf16(h[2], h[3]) & mc;
                cv.u[2] = pack_bf16(h[4], h[5]) & mc;
                cv.u[3] = pack_bf16(h[6], h[7]) & mc;
                af[ks] = cv.s;
            }

            f32x4 acc[4] = {{0.f,0.f,0.f,0.f},{0.f,0.f,0.f,0.f},
                            {0.f,0.f,0.f,0.f},{0.f,0.f,0.f,0.f}};
#pragma unroll
            for (int ks = 0; ks < 3; ++ks)
#pragma unroll
                for (int nt = 0; nt < 4; ++nt)
                    acc[nt] = __builtin_amdgcn_mfma_f32_16x16x32_bf16(
                        af[ks], bf[nt][ks], acc[nt], 0, 0, 0);

            // r = 1/(1+exp(2v)); accumulate
#pragma unroll
            for (int nt = 0; nt < 4; ++nt)
#pragma unroll
                for (int r4 = 0; r4 < 4; ++r4) {
                    float arg = fmaf(acc[nt][r4], TWO_LOG2E, c2[nt]);
                    Rs[nl][nt] += RCPF(1.f + EXP2F(arg));
                }
        }

        // invalid slot (m=255 -> D-row 15 of chunk 3, wave 3): force r to 0.5
        if (w == 3 && hi == 3) {
#pragma unroll
            for (int nt = 0; nt < 4; ++nt) Rs[nl][nt] += corr[nt];
        }
    }

    // ---- final reduction: overlay on sC (all sC reads are done) ----
    __syncthreads();
    float* s_red = (float*)sC;   // [NG][4 waves][64] = 4096 B
#pragma unroll
    for (int nl = 0; nl < NG; ++nl)
#pragma unroll
        for (int nt = 0; nt < 4; ++nt) {
            float v = Rs[nl][nt];
            v += __shfl_xor(v, 16);
            v += __shfl_xor(v, 32);
            Rs[nl][nt] = v;
        }
    if (hi == 0) {
#pragma unroll
        for (int nl = 0; nl < NG; ++nl)
#pragma unroll
            for (int nt = 0; nt < 4; ++nt)
                s_red[(nl * 4 + w) * 64 + nt * 16 + lo16] = Rs[nl][nt];
    }
    __syncthreads();
    {
        int onl = tid >> 6, oo = tid & 63;   // 256 threads = 4 nl x 64 cols
        float t = s_red[(onl * 4 + 0) * 64 + oo] + s_red[(onl * 4 + 1) * 64 + oo]
                + s_red[(onl * 4 + 2) * 64 + oo] + s_red[(onl * 4 + 3) * 64 + oo];
        out[(size_t)((b << 8) + n0 + onl) * FOUT + oo] = fmaf(-2.f, t, 256.f);
    }
}

extern "C" void kernel_launch(void* const* d_in, const int* in_sizes, int n_in,
                              void* d_out, int out_size, void* d_ws, size_t ws_size,
                              hipStream_t stream) {
    const float* inp_node = (const float*)d_in[0];  // (8,256,64)
    const float* inp_edge = (const float*)d_in[1];  // (8,256,255)
    const float* W1       = (const float*)d_in[2];  // (129,96)
    const float* b1       = (const float*)d_in[3];  // (96,)
    const float* W2       = (const float*)d_in[4];  // (96,64)
    const float* b2       = (const float*)d_in[5];  // (64,)
    float* out            = (float*)d_out;          // (8,256,64)

    float* A = (float*)d_ws;                                        // 2048*96 f32
    unsigned short* Cb16 = (unsigned short*)(A + (size_t)BATCH * NN * MIDD); // 2048*CPAD bf16
    unsigned short* W2T  = Cb16 + (size_t)BATCH * NN * CPAD;        // 64*CPAD bf16

    edge_pre<<<BATCH * NN + 1, 192, 0, stream>>>(inp_node, W1, b1, W2, A, Cb16, W2T);
    edge_main3<<<BATCH * (NN / NG), 256, 0, stream>>>(inp_edge, A, Cb16, W1, W2T, b2, out);
}